// Round 9
// baseline (347.608 us; speedup 1.0000x reference)
//
#include <hip/hip_runtime.h>

#define B_ 64
#define T_ 256
#define DIN_ 1024
#define DOUT_ 1024

typedef int v4i  __attribute__((ext_vector_type(4)));
typedef int v16i __attribute__((ext_vector_type(16)));

#define PRE_BYTES 134217728ULL   // 256*1024*64*8
#define XS_BYTES  83886080ULL    // sized for 5 slices; 4 used
#define WSL_BYTES 5242880ULL     // sized for 5 slices; 4 used
#define SPM_BYTES 2097152ULL     // 256*1024*8

// async 16B/lane global->LDS DMA: per-lane global src, wave-uniform LDS base,
// lane i lands at ldsbase + i*16.
__device__ __forceinline__ void async_copy16(const void* g, void* l) {
    __builtin_amdgcn_global_load_lds(
        (const __attribute__((address_space(1))) void*)g,
        (__attribute__((address_space(3))) void*)l, 16, 0, 0);
}

// -----------------------------------------------------------------------------
// Split x into 4 signed-i8 slices, fixed scale 2^3, MFMA A-frag chunk order:
// chunk(s,t,kt,mt) = 1KB, byte = lane*16+j, lane = kh*32+m,
// element = x[b=mt*32+m][t][kt*32+kh*16+j].
// 4 slices = 27 bits; with W's 4 slices and pairs i+j<=3 the pre error is
// ~1.4e-7 rms — far below the fp32 reference's own ~1e-6 einsum error.
// -----------------------------------------------------------------------------
__global__ __launch_bounds__(256) void snn_split_x(
    const float* __restrict__ x, char* __restrict__ xs)
{
    const int W    = blockIdx.x * 4 + (threadIdx.x >> 6);   // 0..16383
    const int lane = threadIdx.x & 63;
    const int mt = W & 1, kt = (W >> 1) & 31, t0 = W >> 6;
    const int m = lane & 31, kh = lane >> 5;
    const int b = mt * 32 + m;

    const float* src = x + ((size_t)b * T_ + t0) * DIN_ + kt * 32 + kh * 16;
    float f[16];
    *(float4*)(f)      = *(const float4*)(src);
    *(float4*)(f + 4)  = *(const float4*)(src + 4);
    *(float4*)(f + 8)  = *(const float4*)(src + 8);
    *(float4*)(f + 12) = *(const float4*)(src + 12);

    unsigned pk[4][4];
#pragma unroll
    for (int s = 0; s < 4; ++s)
        pk[s][0] = pk[s][1] = pk[s][2] = pk[s][3] = 0u;
#pragma unroll
    for (int j = 0; j < 16; ++j) {
        float v = f[j] * 0.125f;                 // / 2^3 (exact)
#pragma unroll
        for (int s = 0; s < 4; ++s) {
            const float ml = (s == 0) ? 64.f : 128.f;
            const float sv = __builtin_rintf(v * ml);
            v = v * ml - sv;                     // exact residual
            const int iv = (int)sv;
            pk[s][j >> 2] |= ((unsigned)iv & 0xffu) << ((j & 3) * 8);
        }
    }
#pragma unroll
    for (int s = 0; s < 4; ++s) {
        char* dst = xs + (size_t)(((s * 256 + t0) * 32 + kt) * 2 + mt) * 1024
                       + lane * 16;
        *(uint4*)dst = make_uint4(pk[s][0], pk[s][1], pk[s][2], pk[s][3]);
    }
}

// -----------------------------------------------------------------------------
// Split W into 4 i8 slices, fixed scale 2^-2, B-frag chunk order:
// chunk(s,ot,kt) = 1KB, element = W[o=ot*32+n][kt*32+kh*16+j].
// -----------------------------------------------------------------------------
__global__ __launch_bounds__(256) void snn_split_w(
    const float* __restrict__ Wt, char* __restrict__ wsl)
{
    const int W    = blockIdx.x * 4 + (threadIdx.x >> 6);   // 0..1023
    const int lane = threadIdx.x & 63;
    const int kt = W & 31, ot = W >> 5;
    const int n = lane & 31, kh = lane >> 5;
    const int o = ot * 32 + n;

    const float* src = Wt + (size_t)o * DIN_ + kt * 32 + kh * 16;
    float f[16];
    *(float4*)(f)      = *(const float4*)(src);
    *(float4*)(f + 4)  = *(const float4*)(src + 4);
    *(float4*)(f + 8)  = *(const float4*)(src + 8);
    *(float4*)(f + 12) = *(const float4*)(src + 12);

    unsigned pk[4][4];
#pragma unroll
    for (int s = 0; s < 4; ++s)
        pk[s][0] = pk[s][1] = pk[s][2] = pk[s][3] = 0u;
#pragma unroll
    for (int j = 0; j < 16; ++j) {
        float v = f[j] * 4.0f;                   // / 2^-2 (exact)
#pragma unroll
        for (int s = 0; s < 4; ++s) {
            const float ml = (s == 0) ? 64.f : 128.f;
            const float sv = __builtin_rintf(v * ml);
            v = v * ml - sv;
            const int iv = (int)sv;
            pk[s][j >> 2] |= ((unsigned)iv & 0xffu) << ((j & 3) * 8);
        }
    }
#pragma unroll
    for (int s = 0; s < 4; ++s) {
        char* dst = wsl + (size_t)((s * 32 + ot) * 32 + kt) * 1024 + lane * 16;
        *(uint4*)dst = make_uint4(pk[s][0], pk[s][1], pk[s][2], pk[s][3]);
    }
}

// -----------------------------------------------------------------------------
// GEMM via i8 MFMA — hybrid pipes: A register-direct (VMEM), B LDS-staged.
// r3/r4/r6/r8 post-mortem: all land at LDS ~52-55 B/cyc/CU effective (reads
// + DMA-writes mixed) with MfmaUtil pinned 43-48% -> the kernel is
// LDS-data-path-bound; schedule changes can't help. Fix: move A (wave-pair-
// private, no block reuse worth staging) off LDS onto the parallel VMEM
// pipe — xs is fragment-ordered so global_load_dwordx4 lands A straight in
// VGPRs (r7-proven path), ping-pong prefetched 1 kt ahead (named aP/aQ).
// B keeps r6's 3-buffer counted-vmcnt LDS path (4-way block reuse, L2-res).
// Per CU-interval @3 blocks/CU: LDS 72 KB (was 176) -> ~760-1330 cyc;
// VMEM A 48 KB issued (~24 unique, L1 dedup); MFMA 1097 cyc.
// vmcnt audit (per wave, A-loads issued BEFORE stage-DMA each interval):
//   steady outstanding at top of kt: D(kt)x2 (oldest), A(kt)x4, D(kt+1)x2
//   -> vmcnt(2) completes D(kt)+A(kt), leaves D(kt+1) in flight. Tail 0.
// LDS buffer lifetime: buf(j mod 3) written by DMA issued @ j-2 (post-
// barrier), read @ j (post-barrier, post-wait), rewritten by DMA @ j+1
// issued AFTER barrier j+1; readers' lgkmcnt (before MFMA) completes pre-
// barrier -> 1 barrier slack, same audit as r6. Single s_barrier per kt.
// Regs ~132 (64 AGPR acc + 32 aP/aQ + 16 b + addr) -> 3 waves/SIMD
// (__launch_bounds__(256,3)), 3 blocks/CU. Grid 4096 = t0*16+oc, oc%8=XCD.
// 4 slices, 10 pair-MFMAs (i+j<=3), same-acc gaps >= 3 -> no dep tail.
// -----------------------------------------------------------------------------
__global__ __launch_bounds__(256, 3) void snn_gemm_i8(
    const char* __restrict__ xs, const char* __restrict__ wsl,
    const float* __restrict__ bias, double* __restrict__ pre)
{
    __shared__ __align__(16) char ldsB[3][8 * 1024];
    const int t0 = blockIdx.x >> 4;
    const int oc = blockIdx.x & 15;          // oc%8 == XCD under round-robin
    const int tid = threadIdx.x;
    const int lane = tid & 63;
    const int ws = __builtin_amdgcn_readfirstlane(tid >> 6);   // 0..3
    const int wm = ws >> 1;                  // b-half (A chunk) this wave uses
    const int wo = ws & 1;                   // local ot (B chunk) this wave uses
    const int lo = lane * 16;

    v16i acc[4];
#pragma unroll
    for (int g = 0; g < 4; ++g)
#pragma unroll
        for (int r = 0; r < 16; ++r) acc[g][r] = 0;

    // A direct-load base (per-lane): xs + s*16MB + t0*65536 + kt*2048 + wm*1024
    const char* ab = xs + (size_t)(t0 * 64 + wm) * 1024 + lo;

    // B staging: 8 chunks/kt (c = ot*4 + s), wave ws stages c = 2*ws, 2*ws+1.
    const int c0 = ws * 2, c1 = ws * 2 + 1;
    const char* sgB0 = wsl + (size_t)(c0 & 3) * 1048576
                           + (size_t)(oc * 2 + (c0 >> 2)) * 32768 + lo;
    const char* sgB1 = wsl + (size_t)(c1 & 3) * 1048576
                           + (size_t)(oc * 2 + (c1 >> 2)) * 32768 + lo;

    v4i aP[4], aQ[4];

#define LOAD_A(R, KT)                                                          \
    do { _Pragma("unroll")                                                     \
        for (int s = 0; s < 4; ++s)                                            \
            R[s] = *(const v4i*)(ab + (size_t)s * 16777216 +                   \
                                 (size_t)(KT) * 2048);                         \
    } while (0)
#define STAGE(JB, BUF)                                                         \
    do {                                                                       \
        async_copy16(sgB0 + (size_t)(JB) * 1024, &ldsB[BUF][c0 * 1024]);       \
        async_copy16(sgB1 + (size_t)(JB) * 1024, &ldsB[BUF][c1 * 1024]);       \
    } while (0)
// order: acc g = 3,2,1,3,2,1,3,2,0,3 — same-acc gaps all >= 3
#define MFMA10(A, B)                                                           \
    do {                                                                       \
        __builtin_amdgcn_s_setprio(1);                                         \
        acc[3] = __builtin_amdgcn_mfma_i32_32x32x32_i8(A[0], B[3], acc[3],0,0,0);\
        acc[2] = __builtin_amdgcn_mfma_i32_32x32x32_i8(A[0], B[2], acc[2],0,0,0);\
        acc[1] = __builtin_amdgcn_mfma_i32_32x32x32_i8(A[0], B[1], acc[1],0,0,0);\
        acc[3] = __builtin_amdgcn_mfma_i32_32x32x32_i8(A[1], B[2], acc[3],0,0,0);\
        acc[2] = __builtin_amdgcn_mfma_i32_32x32x32_i8(A[1], B[1], acc[2],0,0,0);\
        acc[1] = __builtin_amdgcn_mfma_i32_32x32x32_i8(A[1], B[0], acc[1],0,0,0);\
        acc[3] = __builtin_amdgcn_mfma_i32_32x32x32_i8(A[2], B[1], acc[3],0,0,0);\
        acc[2] = __builtin_amdgcn_mfma_i32_32x32x32_i8(A[2], B[0], acc[2],0,0,0);\
        acc[0] = __builtin_amdgcn_mfma_i32_32x32x32_i8(A[0], B[0], acc[0],0,0,0);\
        acc[3] = __builtin_amdgcn_mfma_i32_32x32x32_i8(A[3], B[0], acc[3],0,0,0);\
        __builtin_amdgcn_s_setprio(0);                                         \
    } while (0)
// one K-step: wait own A(kt)+D(kt), barrier, prefetch A(kt+1), stage kt+2,
// ds_read B(kt), MFMA on A-cur. A-loads BEFORE stage keeps vmcnt order fixed.
#define INTERVAL(KT, ACUR, ANXT)                                               \
    do {                                                                       \
        if ((KT) < 31) asm volatile("s_waitcnt vmcnt(2)" ::: "memory");        \
        else           asm volatile("s_waitcnt vmcnt(0)" ::: "memory");        \
        __builtin_amdgcn_s_barrier();                                          \
        asm volatile("" ::: "memory");                                         \
        if ((KT) + 1 < 32) LOAD_A(ANXT, (KT) + 1);                             \
        if ((KT) + 2 < 32) STAGE((KT) + 2, st);                                \
        const char* bufB = ldsB[rd];                                           \
        v4i b[4];                                                              \
        _Pragma("unroll")                                                      \
        for (int s = 0; s < 4; ++s)                                            \
            b[s] = *(const v4i*)(bufB + (wo * 4 + s) * 1024 + lo);             \
        MFMA10(ACUR, b);                                                       \
        rd = (rd == 2) ? 0 : rd + 1;                                           \
        st = (st == 2) ? 0 : st + 1;                                           \
    } while (0)

    // prologue: A(0) first (oldest in vmcnt order), then DMA batches 0,1.
    LOAD_A(aP, 0);
    STAGE(0, 0);
    STAGE(1, 1);

    int rd = 0, st = 2;
    for (int ks = 0; ks < 16; ++ks) {
        INTERVAL(2 * ks,     aP, aQ);
        INTERVAL(2 * ks + 1, aQ, aP);
    }
#undef INTERVAL
#undef MFMA10
#undef STAGE
#undef LOAD_A

    // epilogue: D layout col=lane&31 (o), row=(r&3)+8*(r>>2)+4*(lane>>5) (b)
    const int n = lane & 31, lh = lane >> 5;
    const int o = oc * 64 + wo * 32 + n;
    const double bv = (double)bias[o];
    double* dst = pre + ((size_t)t0 * DOUT_ + o) * 64 + wm * 32;
#pragma unroll
    for (int r = 0; r < 16; ++r) {
        const int row = (r & 3) + 8 * (r >> 2) + 4 * lh;
        double v = (double)acc[3][r];
        v = v * 0.0078125 + (double)acc[2][r];
        v = v * 0.0078125 + (double)acc[1][r];
        v = v * 0.0078125 + (double)acc[0][r];
        dst[row] = v * 0x1p-11 + bv;             // 2^{3-2-12}
    }
}

// -----------------------------------------------------------------------------
// Fallback GEMM (round-8 proven fp64-VALU path), used when ws is small.
// -----------------------------------------------------------------------------
__global__ __launch_bounds__(256, 2) void snn_gemm_fb(
    const float* __restrict__ x, const float* __restrict__ W,
    const float* __restrict__ bias, double* __restrict__ pre)
{
    __shared__ float smem[2][8 * 72 + 8 * 256];
    const int t0 = blockIdx.x & 255;
    const int o0 = blockIdx.x >> 8;
    const int tid = threadIdx.x;
    const int to = tid & 31;
    const int tb = tid >> 5;

    double acc[8][8];
#pragma unroll
    for (int i = 0; i < 8; ++i)
#pragma unroll
        for (int j = 0; j < 8; ++j) acc[i][j] = 0.0;

    const int arow = tid >> 2;
    const int ak2  = (tid & 3) * 2;
    const float* xg = x + (size_t)(t0 + 256 * arow) * DIN_ + ak2;
    const float* wg = W + (size_t)(o0 * 256 + tid) * DIN_;

    float2 f2  = *(const float2*)(xg);
    float4 bq0 = *(const float4*)(wg);
    float4 bq1 = *(const float4*)(wg + 4);

    for (int kc = 0; kc < DIN_ / 8; ++kc) {
        float* base = smem[kc & 1];
        float (*AsF)[72]  = (float(*)[72])base;
        float (*BsF)[256] = (float(*)[256])(base + 8 * 72);
        AsF[ak2 + 0][arow] = f2.x;
        AsF[ak2 + 1][arow] = f2.y;
        BsF[0][tid] = bq0.x;  BsF[1][tid] = bq0.y;
        BsF[2][tid] = bq0.z;  BsF[3][tid] = bq0.w;
        BsF[4][tid] = bq1.x;  BsF[5][tid] = bq1.y;
        BsF[6][tid] = bq1.z;  BsF[7][tid] = bq1.w;
        __syncthreads();
        if (kc + 1 < DIN_ / 8) {
            f2  = *(const float2*)(xg + (kc + 1) * 8);
            bq0 = *(const float4*)(wg + (kc + 1) * 8);
            bq1 = *(const float4*)(wg + (kc + 1) * 8 + 4);
        }
#pragma unroll
        for (int k = 0; k < 8; ++k) {
            const float4 af0 = *(const float4*)&AsF[k][tb * 8];
            const float4 af1 = *(const float4*)&AsF[k][tb * 8 + 4];
            const float4 bf0 = *(const float4*)&BsF[k][to * 4];
            const float4 bf1 = *(const float4*)&BsF[k][128 + to * 4];
            double a[8], b[8];
            a[0] = (double)af0.x; a[1] = (double)af0.y;
            a[2] = (double)af0.z; a[3] = (double)af0.w;
            a[4] = (double)af1.x; a[5] = (double)af1.y;
            a[6] = (double)af1.z; a[7] = (double)af1.w;
            b[0] = (double)bf0.x; b[1] = (double)bf0.y;
            b[2] = (double)bf0.z; b[3] = (double)bf0.w;
            b[4] = (double)bf1.x; b[5] = (double)bf1.y;
            b[6] = (double)bf1.z; b[7] = (double)bf1.w;
#pragma unroll
            for (int i = 0; i < 8; ++i)
#pragma unroll
                for (int j = 0; j < 8; ++j)
                    acc[i][j] += a[i] * b[j];
        }
        __syncthreads();
    }

    double biasd[8];
#pragma unroll
    for (int j = 0; j < 8; ++j)
        biasd[j] = (double)bias[o0 * 256 + (j >> 2) * 128 + to * 4 + (j & 3)];
    double (*trans)[67] = (double(*)[67])smem[0];
    for (int c = 0; c < 16; ++c) {
        __syncthreads();
        const int j4  = c >> 3;
        const int tlo = (c & 7) * 4;
        if (to >= tlo && to < tlo + 4) {
#pragma unroll
            for (int p4 = 0; p4 < 4; ++p4) {
                const int r = (to - tlo) * 4 + p4;
                const int j = j4 * 4 + p4;
#pragma unroll
                for (int i = 0; i < 8; ++i)
                    trans[r][tb * 8 + i] = acc[i][j] + biasd[j];
            }
        }
        __syncthreads();
#pragma unroll
        for (int q = 0; q < 4; ++q) {
            const int idx = tid + 256 * q;
            const int b  = idx & 63;
            const int oc = idx >> 6;
            pre[(size_t)(t0 * DOUT_ + o0 * 256 + c * 16 + oc) * 64 + b] = trans[oc][b];
        }
    }
}

// -----------------------------------------------------------------------------
// Scan: one wave per o, lane = b. Batch-mean via ballot+popcount.
// Software-pipelined 16-deep load batches (two NAMED arrays -> registers,
// never runtime-indexed).
// -----------------------------------------------------------------------------
#define SCAN_LOAD(PV, TB)                                                      \
    do {                                                                       \
        _Pragma("unroll")                                                      \
        for (int j = 0; j < 16; ++j)                                           \
            PV[j] = p[(size_t)((TB) + j) * (DOUT_ * 64)];                      \
    } while (0)

#define SCAN_STEP(PV, TB)                                                      \
    do {                                                                       \
        _Pragma("unroll")                                                      \
        for (int j = 0; j < 16; ++j) {                                         \
            mem += PV[j];                                                      \
            const bool s = (mem >= thr);                                       \
            const unsigned long long msk = __ballot(s);                        \
            thr += 0.05 * ((double)__popcll(msk) * (1.0 / 64.0) - 0.5);        \
            if (spM) {                                                         \
                if (lane == 0) spM[(size_t)((TB) + j) * DOUT_ + o] = msk;      \
            } else {                                                           \
                outD[(size_t)lane * (T_ * DOUT_) +                             \
                     (size_t)((TB) + j) * DOUT_ + o] = s ? 1.0f : 0.0f;        \
            }                                                                  \
            mem = s ? 0.0 : mem;                                               \
        }                                                                      \
    } while (0)

__global__ __launch_bounds__(256) void snn_scan(
    const double* __restrict__ pre, const float* __restrict__ thr_in,
    unsigned long long* __restrict__ spM, float* __restrict__ outD)
{
    const int wid  = (blockIdx.x * blockDim.x + threadIdx.x) >> 6;
    const int lane = threadIdx.x & 63;
    if (wid >= DOUT_) return;
    const int o = wid;

    double mem = 0.0;
    double thr = (double)thr_in[o];
    const double* p = pre + (size_t)o * 64 + lane;

    double pvA[16], pvB[16];
    SCAN_LOAD(pvA, 0);
    for (int t = 0; t < T_; t += 32) {
        if (t + 16 < T_) SCAN_LOAD(pvB, t + 16);
        SCAN_STEP(pvA, t);
        if (t + 32 < T_) SCAN_LOAD(pvA, t + 32);
        SCAN_STEP(pvB, t + 16);
    }
}

// -----------------------------------------------------------------------------
// Expand: thread = (t, o-group-of-4). Reads 4 masks (32B/lane contiguous),
// writes float4 per b (16B/lane, 1KB/wave contiguous stores).
// -----------------------------------------------------------------------------
__global__ __launch_bounds__(256) void snn_expand(
    const unsigned long long* __restrict__ spM, float* __restrict__ out)
{
    const int idx = blockIdx.x * 256 + threadIdx.x;  // 0..65535
    const int og = idx & 255;                        // o/4
    const int t  = idx >> 8;
    const unsigned long long* mp = spM + (size_t)t * DOUT_ + og * 4;
    const unsigned long long m0 = mp[0], m1 = mp[1], m2 = mp[2], m3 = mp[3];
    float* op = out + (size_t)t * DOUT_ + og * 4;
#pragma unroll
    for (int b = 0; b < 64; ++b) {
        float4 v;
        v.x = (float)((m0 >> b) & 1ULL);
        v.y = (float)((m1 >> b) & 1ULL);
        v.z = (float)((m2 >> b) & 1ULL);
        v.w = (float)((m3 >> b) & 1ULL);
        *(float4*)(op + (size_t)b * (T_ * DOUT_)) = v;
    }
}

extern "C" void kernel_launch(void* const* d_in, const int* in_sizes, int n_in,
                              void* d_out, int out_size, void* d_ws, size_t ws_size,
                              hipStream_t stream) {
    const float* x    = (const float*)d_in[0];   // [64][256][1024]
    const float* W    = (const float*)d_in[1];   // [1024][1024]
    const float* bias = (const float*)d_in[2];   // [1024]
    const float* thr  = (const float*)d_in[3];   // [1024]
    float* out = (float*)d_out;                  // [64][256][1024]

    double* pre = (double*)d_ws;
    const size_t need = PRE_BYTES + XS_BYTES + WSL_BYTES + SPM_BYTES;

    if (ws_size >= need) {
        char* xs  = (char*)d_ws + PRE_BYTES;
        char* wsl = xs + XS_BYTES;
        unsigned long long* spM = (unsigned long long*)(wsl + WSL_BYTES);
        snn_split_x<<<4096, 256, 0, stream>>>(x, xs);
        snn_split_w<<<256, 256, 0, stream>>>(W, wsl);
        snn_gemm_i8<<<4096, 256, 0, stream>>>(xs, wsl, bias, pre);
        snn_scan<<<256, 256, 0, stream>>>(pre, thr, spM, nullptr);
        snn_expand<<<256, 256, 0, stream>>>(spM, out);
    } else {
        const bool two_stage = (ws_size >= PRE_BYTES + SPM_BYTES);
        unsigned long long* spM =
            two_stage ? (unsigned long long*)((char*)d_ws + PRE_BYTES) : nullptr;
        snn_gemm_fb<<<1024, 256, 0, stream>>>(x, W, bias, pre);
        snn_scan<<<256, 256, 0, stream>>>(pre, thr, spM, two_stage ? nullptr : out);
        if (two_stage)
            snn_expand<<<1024, 256, 0, stream>>>(spM, out);
    }
}

// Round 11
// 337.971 us; speedup vs baseline: 1.0285x; 1.0285x over previous
//
#include <hip/hip_runtime.h>

#define B_ 64
#define T_ 256
#define DIN_ 1024
#define DOUT_ 1024

typedef int v4i  __attribute__((ext_vector_type(4)));
typedef int v16i __attribute__((ext_vector_type(16)));

#define PRE_BYTES 134217728ULL   // 256*1024*64*8
#define XS_BYTES  83886080ULL    // sized for 5 slices; 4 used
#define WSL_BYTES 5242880ULL     // sized for 5 slices; 4 used
#define SPM_BYTES 2097152ULL     // 256*1024*8

// async 16B/lane global->LDS DMA: per-lane global src, wave-uniform LDS base,
// lane i lands at ldsbase + i*16.
__device__ __forceinline__ void async_copy16(const void* g, void* l) {
    __builtin_amdgcn_global_load_lds(
        (const __attribute__((address_space(1))) void*)g,
        (__attribute__((address_space(3))) void*)l, 16, 0, 0);
}

// -----------------------------------------------------------------------------
// Split x into 4 signed-i8 slices, fixed scale 2^3, MFMA A-frag chunk order:
// chunk(s,t,kt,mt) = 1KB, byte = lane*16+j, lane = kh*32+m,
// element = x[b=mt*32+m][t][kt*32+kh*16+j].
// 4 slices = 27 bits; with W's 4 slices and pairs i+j<=3 the pre error is
// ~1.4e-7 rms — far below the fp32 reference's own ~1e-6 einsum error.
// -----------------------------------------------------------------------------
__global__ __launch_bounds__(256) void snn_split_x(
    const float* __restrict__ x, char* __restrict__ xs)
{
    const int W    = blockIdx.x * 4 + (threadIdx.x >> 6);   // 0..16383
    const int lane = threadIdx.x & 63;
    const int mt = W & 1, kt = (W >> 1) & 31, t0 = W >> 6;
    const int m = lane & 31, kh = lane >> 5;
    const int b = mt * 32 + m;

    const float* src = x + ((size_t)b * T_ + t0) * DIN_ + kt * 32 + kh * 16;
    float f[16];
    *(float4*)(f)      = *(const float4*)(src);
    *(float4*)(f + 4)  = *(const float4*)(src + 4);
    *(float4*)(f + 8)  = *(const float4*)(src + 8);
    *(float4*)(f + 12) = *(const float4*)(src + 12);

    unsigned pk[4][4];
#pragma unroll
    for (int s = 0; s < 4; ++s)
        pk[s][0] = pk[s][1] = pk[s][2] = pk[s][3] = 0u;
#pragma unroll
    for (int j = 0; j < 16; ++j) {
        float v = f[j] * 0.125f;                 // / 2^3 (exact)
#pragma unroll
        for (int s = 0; s < 4; ++s) {
            const float ml = (s == 0) ? 64.f : 128.f;
            const float sv = __builtin_rintf(v * ml);
            v = v * ml - sv;                     // exact residual
            const int iv = (int)sv;
            pk[s][j >> 2] |= ((unsigned)iv & 0xffu) << ((j & 3) * 8);
        }
    }
#pragma unroll
    for (int s = 0; s < 4; ++s) {
        char* dst = xs + (size_t)(((s * 256 + t0) * 32 + kt) * 2 + mt) * 1024
                       + lane * 16;
        *(uint4*)dst = make_uint4(pk[s][0], pk[s][1], pk[s][2], pk[s][3]);
    }
}

// -----------------------------------------------------------------------------
// Split W into 4 i8 slices, fixed scale 2^-2, B-frag chunk order:
// chunk(s,ot,kt) = 1KB, element = W[o=ot*32+n][kt*32+kh*16+j].
// -----------------------------------------------------------------------------
__global__ __launch_bounds__(256) void snn_split_w(
    const float* __restrict__ Wt, char* __restrict__ wsl)
{
    const int W    = blockIdx.x * 4 + (threadIdx.x >> 6);   // 0..1023
    const int lane = threadIdx.x & 63;
    const int kt = W & 31, ot = W >> 5;
    const int n = lane & 31, kh = lane >> 5;
    const int o = ot * 32 + n;

    const float* src = Wt + (size_t)o * DIN_ + kt * 32 + kh * 16;
    float f[16];
    *(float4*)(f)      = *(const float4*)(src);
    *(float4*)(f + 4)  = *(const float4*)(src + 4);
    *(float4*)(f + 8)  = *(const float4*)(src + 8);
    *(float4*)(f + 12) = *(const float4*)(src + 12);

    unsigned pk[4][4];
#pragma unroll
    for (int s = 0; s < 4; ++s)
        pk[s][0] = pk[s][1] = pk[s][2] = pk[s][3] = 0u;
#pragma unroll
    for (int j = 0; j < 16; ++j) {
        float v = f[j] * 4.0f;                   // / 2^-2 (exact)
#pragma unroll
        for (int s = 0; s < 4; ++s) {
            const float ml = (s == 0) ? 64.f : 128.f;
            const float sv = __builtin_rintf(v * ml);
            v = v * ml - sv;
            const int iv = (int)sv;
            pk[s][j >> 2] |= ((unsigned)iv & 0xffu) << ((j & 3) * 8);
        }
    }
#pragma unroll
    for (int s = 0; s < 4; ++s) {
        char* dst = wsl + (size_t)((s * 32 + ot) * 32 + kt) * 1024 + lane * 16;
        *(uint4*)dst = make_uint4(pk[s][0], pk[s][1], pk[s][2], pk[s][3]);
    }
}

// -----------------------------------------------------------------------------
// GEMM via i8 MFMA — hybrid pipes: A register-direct 3-deep, B LDS-staged.
// r9 post-mortem: halving LDS bytes didn't help because A's reg-loads had
// only 1-interval (~900 cyc) cover == L3-miss latency (pre-write stream
// evicts xs; FETCH=4x inputs confirms) -> every interval exposed A latency
// and the barrier convoyed the block. r6/r8 covered A 2 intervals but paid
// 2x LDS. This round = r9 + 3-deep A pipeline: BOTH thin LDS AND 2-interval
// cover. A: aP/aQ/aR named reg sets (static indexing), issue-ahead-2.
// B: 3-buffer LDS via global_load_lds, issue-ahead-2 (unchanged from r9).
// vmcnt audit (per wave, per interval issue order: A(kt+2)x4, D(kt+2)x2):
//   top of kt outstanding (old->new): A(kt)4, D(kt)2, A(kt+1)4, D(kt+1)2
//   -> vmcnt(6) completes A(kt)+D(kt), leaves 6 in flight across barrier.
//   kt=31: only A(31)+D(31) remain -> vmcnt(0).
// LDS lifetime: buf j%3 DMA'd @ j-2 (post-barrier), read @ j (lgkmcnt'd
// before MFMA -> done pre-barrier j+1), re-DMA'd @ j+1 for batch j+3 ->
// one barrier slack. Single s_barrier per kt.
// Budget/CU: LDS 12.3 MB total (~93 us at measured 55 B/cyc mixed rate),
// MFMA 187k cyc (78 us), VMEM A 48 KB/interval issued (L1 dedup within
// wave-pair). Regs ~150 (64 acc + 48 A + 16 b) -> 3 waves/SIMD
// (__launch_bounds__(256,3)), 3 blocks/CU. Grid 4096 = t0*16+oc, oc%8=XCD.
// 4 slices, 10 pair-MFMAs (i+j<=3), same-acc gaps >= 3 -> no dep tail.
// -----------------------------------------------------------------------------
__global__ __launch_bounds__(256, 3) void snn_gemm_i8(
    const char* __restrict__ xs, const char* __restrict__ wsl,
    const float* __restrict__ bias, double* __restrict__ pre)
{
    __shared__ __align__(16) char ldsB[3][8 * 1024];
    const int t0 = blockIdx.x >> 4;
    const int oc = blockIdx.x & 15;          // oc%8 == XCD under round-robin
    const int tid = threadIdx.x;
    const int lane = tid & 63;
    const int ws = __builtin_amdgcn_readfirstlane(tid >> 6);   // 0..3
    const int wm = ws >> 1;                  // b-half (A chunk) this wave uses
    const int wo = ws & 1;                   // local ot (B chunk) this wave uses
    const int lo = lane * 16;

    v16i acc[4];
#pragma unroll
    for (int g = 0; g < 4; ++g)
#pragma unroll
        for (int r = 0; r < 16; ++r) acc[g][r] = 0;

    // A direct-load base (per-lane): xs + s*16MB + t0*65536 + kt*2048 + wm*1024
    const char* ab = xs + (size_t)(t0 * 64 + wm) * 1024 + lo;

    // B staging: 8 chunks/kt (c = ot*4 + s), wave ws stages c = 2*ws, 2*ws+1.
    const int c0 = ws * 2, c1 = ws * 2 + 1;
    const char* sgB0 = wsl + (size_t)(c0 & 3) * 1048576
                           + (size_t)(oc * 2 + (c0 >> 2)) * 32768 + lo;
    const char* sgB1 = wsl + (size_t)(c1 & 3) * 1048576
                           + (size_t)(oc * 2 + (c1 >> 2)) * 32768 + lo;

    v4i aP[4], aQ[4], aR[4];

#define LOAD_A(R, KT)                                                          \
    do { _Pragma("unroll")                                                     \
        for (int s = 0; s < 4; ++s)                                            \
            R[s] = *(const v4i*)(ab + (size_t)s * 16777216 +                   \
                                 (size_t)(KT) * 2048);                         \
    } while (0)
#define STAGE(JB, BUF)                                                         \
    do {                                                                       \
        async_copy16(sgB0 + (size_t)(JB) * 1024, &ldsB[BUF][c0 * 1024]);       \
        async_copy16(sgB1 + (size_t)(JB) * 1024, &ldsB[BUF][c1 * 1024]);       \
    } while (0)
// order: acc g = 3,2,1,3,2,1,3,2,0,3 — same-acc gaps all >= 3
#define MFMA10(A, B)                                                           \
    do {                                                                       \
        __builtin_amdgcn_s_setprio(1);                                         \
        acc[3] = __builtin_amdgcn_mfma_i32_32x32x32_i8(A[0], B[3], acc[3],0,0,0);\
        acc[2] = __builtin_amdgcn_mfma_i32_32x32x32_i8(A[0], B[2], acc[2],0,0,0);\
        acc[1] = __builtin_amdgcn_mfma_i32_32x32x32_i8(A[0], B[1], acc[1],0,0,0);\
        acc[3] = __builtin_amdgcn_mfma_i32_32x32x32_i8(A[1], B[2], acc[3],0,0,0);\
        acc[2] = __builtin_amdgcn_mfma_i32_32x32x32_i8(A[1], B[1], acc[2],0,0,0);\
        acc[1] = __builtin_amdgcn_mfma_i32_32x32x32_i8(A[1], B[0], acc[1],0,0,0);\
        acc[3] = __builtin_amdgcn_mfma_i32_32x32x32_i8(A[2], B[1], acc[3],0,0,0);\
        acc[2] = __builtin_amdgcn_mfma_i32_32x32x32_i8(A[2], B[0], acc[2],0,0,0);\
        acc[0] = __builtin_amdgcn_mfma_i32_32x32x32_i8(A[0], B[0], acc[0],0,0,0);\
        acc[3] = __builtin_amdgcn_mfma_i32_32x32x32_i8(A[3], B[0], acc[3],0,0,0);\
        __builtin_amdgcn_s_setprio(0);                                         \
    } while (0)
// one K-step: wait A(kt)+D(kt) (issued 2 intervals ago), barrier, issue
// A(kt+2)+D(kt+2), ds_read B(kt), MFMA on A-cur. 2-interval latency cover.
#define INTERVAL(KT, ACUR, ANXT)                                               \
    do {                                                                       \
        if ((KT) < 31) asm volatile("s_waitcnt vmcnt(6)" ::: "memory");        \
        else           asm volatile("s_waitcnt vmcnt(0)" ::: "memory");        \
        __builtin_amdgcn_s_barrier();                                          \
        asm volatile("" ::: "memory");                                         \
        if ((KT) + 2 < 32) {                                                   \
            LOAD_A(ANXT, (KT) + 2);                                            \
            STAGE((KT) + 2, st);                                               \
        }                                                                      \
        const char* bufB = ldsB[rd];                                           \
        v4i b[4];                                                              \
        _Pragma("unroll")                                                      \
        for (int s = 0; s < 4; ++s)                                            \
            b[s] = *(const v4i*)(bufB + (wo * 4 + s) * 1024 + lo);             \
        MFMA10(ACUR, b);                                                       \
        rd = (rd == 2) ? 0 : rd + 1;                                           \
        st = (st == 2) ? 0 : st + 1;                                           \
    } while (0)

    // prologue: A(0),D(0),A(1),D(1) in vmcnt-oldest-first order (12 loads)
    LOAD_A(aP, 0);
    STAGE(0, 0);
    LOAD_A(aQ, 1);
    STAGE(1, 1);

    int rd = 0, st = 2;
    // rotation: kt=3k -> aP, 3k+1 -> aQ, 3k+2 -> aR; next2 goes to cur+2 set
    for (int ks = 0; ks < 10; ++ks) {
        INTERVAL(3 * ks,     aP, aR);
        INTERVAL(3 * ks + 1, aQ, aP);
        INTERVAL(3 * ks + 2, aR, aQ);
    }
    INTERVAL(30, aP, aR);
    INTERVAL(31, aQ, aP);
#undef INTERVAL
#undef MFMA10
#undef STAGE
#undef LOAD_A

    // epilogue: D layout col=lane&31 (o), row=(r&3)+8*(r>>2)+4*(lane>>5) (b)
    const int n = lane & 31, lh = lane >> 5;
    const int o = oc * 64 + wo * 32 + n;
    const double bv = (double)bias[o];
    double* dst = pre + ((size_t)t0 * DOUT_ + o) * 64 + wm * 32;
#pragma unroll
    for (int r = 0; r < 16; ++r) {
        const int row = (r & 3) + 8 * (r >> 2) + 4 * lh;
        double v = (double)acc[3][r];
        v = v * 0.0078125 + (double)acc[2][r];
        v = v * 0.0078125 + (double)acc[1][r];
        v = v * 0.0078125 + (double)acc[0][r];
        dst[row] = v * 0x1p-11 + bv;             // 2^{3-2-12}
    }
}

// -----------------------------------------------------------------------------
// Fallback GEMM (round-8 proven fp64-VALU path), used when ws is small.
// -----------------------------------------------------------------------------
__global__ __launch_bounds__(256, 2) void snn_gemm_fb(
    const float* __restrict__ x, const float* __restrict__ W,
    const float* __restrict__ bias, double* __restrict__ pre)
{
    __shared__ float smem[2][8 * 72 + 8 * 256];
    const int t0 = blockIdx.x & 255;
    const int o0 = blockIdx.x >> 8;
    const int tid = threadIdx.x;
    const int to = tid & 31;
    const int tb = tid >> 5;

    double acc[8][8];
#pragma unroll
    for (int i = 0; i < 8; ++i)
#pragma unroll
        for (int j = 0; j < 8; ++j) acc[i][j] = 0.0;

    const int arow = tid >> 2;
    const int ak2  = (tid & 3) * 2;
    const float* xg = x + (size_t)(t0 + 256 * arow) * DIN_ + ak2;
    const float* wg = W + (size_t)(o0 * 256 + tid) * DIN_;

    float2 f2  = *(const float2*)(xg);
    float4 bq0 = *(const float4*)(wg);
    float4 bq1 = *(const float4*)(wg + 4);

    for (int kc = 0; kc < DIN_ / 8; ++kc) {
        float* base = smem[kc & 1];
        float (*AsF)[72]  = (float(*)[72])base;
        float (*BsF)[256] = (float(*)[256])(base + 8 * 72);
        AsF[ak2 + 0][arow] = f2.x;
        AsF[ak2 + 1][arow] = f2.y;
        BsF[0][tid] = bq0.x;  BsF[1][tid] = bq0.y;
        BsF[2][tid] = bq0.z;  BsF[3][tid] = bq0.w;
        BsF[4][tid] = bq1.x;  BsF[5][tid] = bq1.y;
        BsF[6][tid] = bq1.z;  BsF[7][tid] = bq1.w;
        __syncthreads();
        if (kc + 1 < DIN_ / 8) {
            f2  = *(const float2*)(xg + (kc + 1) * 8);
            bq0 = *(const float4*)(wg + (kc + 1) * 8);
            bq1 = *(const float4*)(wg + (kc + 1) * 8 + 4);
        }
#pragma unroll
        for (int k = 0; k < 8; ++k) {
            const float4 af0 = *(const float4*)&AsF[k][tb * 8];
            const float4 af1 = *(const float4*)&AsF[k][tb * 8 + 4];
            const float4 bf0 = *(const float4*)&BsF[k][to * 4];
            const float4 bf1 = *(const float4*)&BsF[k][128 + to * 4];
            double a[8], b[8];
            a[0] = (double)af0.x; a[1] = (double)af0.y;
            a[2] = (double)af0.z; a[3] = (double)af0.w;
            a[4] = (double)af1.x; a[5] = (double)af1.y;
            a[6] = (double)af1.z; a[7] = (double)af1.w;
            b[0] = (double)bf0.x; b[1] = (double)bf0.y;
            b[2] = (double)bf0.z; b[3] = (double)bf0.w;
            b[4] = (double)bf1.x; b[5] = (double)bf1.y;
            b[6] = (double)bf1.z; b[7] = (double)bf1.w;
#pragma unroll
            for (int i = 0; i < 8; ++i)
#pragma unroll
                for (int j = 0; j < 8; ++j)
                    acc[i][j] += a[i] * b[j];
        }
        __syncthreads();
    }

    double biasd[8];
#pragma unroll
    for (int j = 0; j < 8; ++j)
        biasd[j] = (double)bias[o0 * 256 + (j >> 2) * 128 + to * 4 + (j & 3)];
    double (*trans)[67] = (double(*)[67])smem[0];
    for (int c = 0; c < 16; ++c) {
        __syncthreads();
        const int j4  = c >> 3;
        const int tlo = (c & 7) * 4;
        if (to >= tlo && to < tlo + 4) {
#pragma unroll
            for (int p4 = 0; p4 < 4; ++p4) {
                const int r = (to - tlo) * 4 + p4;
                const int j = j4 * 4 + p4;
#pragma unroll
                for (int i = 0; i < 8; ++i)
                    trans[r][tb * 8 + i] = acc[i][j] + biasd[j];
            }
        }
        __syncthreads();
#pragma unroll
        for (int q = 0; q < 4; ++q) {
            const int idx = tid + 256 * q;
            const int b  = idx & 63;
            const int oc = idx >> 6;
            pre[(size_t)(t0 * DOUT_ + o0 * 256 + c * 16 + oc) * 64 + b] = trans[oc][b];
        }
    }
}

// -----------------------------------------------------------------------------
// Scan: one wave per o, lane = b. Batch-mean via ballot+popcount.
// Software-pipelined 16-deep load batches (two NAMED arrays -> registers,
// never runtime-indexed).
// -----------------------------------------------------------------------------
#define SCAN_LOAD(PV, TB)                                                      \
    do {                                                                       \
        _Pragma("unroll")                                                      \
        for (int j = 0; j < 16; ++j)                                           \
            PV[j] = p[(size_t)((TB) + j) * (DOUT_ * 64)];                      \
    } while (0)

#define SCAN_STEP(PV, TB)                                                      \
    do {                                                                       \
        _Pragma("unroll")                                                      \
        for (int j = 0; j < 16; ++j) {                                         \
            mem += PV[j];                                                      \
            const bool s = (mem >= thr);                                       \
            const unsigned long long msk = __ballot(s);                        \
            thr += 0.05 * ((double)__popcll(msk) * (1.0 / 64.0) - 0.5);        \
            if (spM) {                                                         \
                if (lane == 0) spM[(size_t)((TB) + j) * DOUT_ + o] = msk;      \
            } else {                                                           \
                outD[(size_t)lane * (T_ * DOUT_) +                             \
                     (size_t)((TB) + j) * DOUT_ + o] = s ? 1.0f : 0.0f;        \
            }                                                                  \
            mem = s ? 0.0 : mem;                                               \
        }                                                                      \
    } while (0)

__global__ __launch_bounds__(256) void snn_scan(
    const double* __restrict__ pre, const float* __restrict__ thr_in,
    unsigned long long* __restrict__ spM, float* __restrict__ outD)
{
    const int wid  = (blockIdx.x * blockDim.x + threadIdx.x) >> 6;
    const int lane = threadIdx.x & 63;
    if (wid >= DOUT_) return;
    const int o = wid;

    double mem = 0.0;
    double thr = (double)thr_in[o];
    const double* p = pre + (size_t)o * 64 + lane;

    double pvA[16], pvB[16];
    SCAN_LOAD(pvA, 0);
    for (int t = 0; t < T_; t += 32) {
        if (t + 16 < T_) SCAN_LOAD(pvB, t + 16);
        SCAN_STEP(pvA, t);
        if (t + 32 < T_) SCAN_LOAD(pvA, t + 32);
        SCAN_STEP(pvB, t + 16);
    }
}

// -----------------------------------------------------------------------------
// Expand: thread = (t, o-group-of-4). Reads 4 masks (32B/lane contiguous),
// writes float4 per b (16B/lane, 1KB/wave contiguous stores).
// -----------------------------------------------------------------------------
__global__ __launch_bounds__(256) void snn_expand(
    const unsigned long long* __restrict__ spM, float* __restrict__ out)
{
    const int idx = blockIdx.x * 256 + threadIdx.x;  // 0..65535
    const int og = idx & 255;                        // o/4
    const int t  = idx >> 8;
    const unsigned long long* mp = spM + (size_t)t * DOUT_ + og * 4;
    const unsigned long long m0 = mp[0], m1 = mp[1], m2 = mp[2], m3 = mp[3];
    float* op = out + (size_t)t * DOUT_ + og * 4;
#pragma unroll
    for (int b = 0; b < 64; ++b) {
        float4 v;
        v.x = (float)((m0 >> b) & 1ULL);
        v.y = (float)((m1 >> b) & 1ULL);
        v.z = (float)((m2 >> b) & 1ULL);
        v.w = (float)((m3 >> b) & 1ULL);
        *(float4*)(op + (size_t)b * (T_ * DOUT_)) = v;
    }
}

extern "C" void kernel_launch(void* const* d_in, const int* in_sizes, int n_in,
                              void* d_out, int out_size, void* d_ws, size_t ws_size,
                              hipStream_t stream) {
    const float* x    = (const float*)d_in[0];   // [64][256][1024]
    const float* W    = (const float*)d_in[1];   // [1024][1024]
    const float* bias = (const float*)d_in[2];   // [1024]
    const float* thr  = (const float*)d_in[3];   // [1024]
    float* out = (float*)d_out;                  // [64][256][1024]

    double* pre = (double*)d_ws;
    const size_t need = PRE_BYTES + XS_BYTES + WSL_BYTES + SPM_BYTES;

    if (ws_size >= need) {
        char* xs  = (char*)d_ws + PRE_BYTES;
        char* wsl = xs + XS_BYTES;
        unsigned long long* spM = (unsigned long long*)(wsl + WSL_BYTES);
        snn_split_x<<<4096, 256, 0, stream>>>(x, xs);
        snn_split_w<<<256, 256, 0, stream>>>(W, wsl);
        snn_gemm_i8<<<4096, 256, 0, stream>>>(xs, wsl, bias, pre);
        snn_scan<<<256, 256, 0, stream>>>(pre, thr, spM, nullptr);
        snn_expand<<<256, 256, 0, stream>>>(spM, out);
    } else {
        const bool two_stage = (ws_size >= PRE_BYTES + SPM_BYTES);
        unsigned long long* spM =
            two_stage ? (unsigned long long*)((char*)d_ws + PRE_BYTES) : nullptr;
        snn_gemm_fb<<<1024, 256, 0, stream>>>(x, W, bias, pre);
        snn_scan<<<256, 256, 0, stream>>>(pre, thr, spM, two_stage ? nullptr : out);
        if (two_stage)
            snn_expand<<<1024, 256, 0, stream>>>(spM, out);
    }
}